// Round 1
// baseline (448.255 us; speedup 1.0000x reference)
//
#include <hip/hip_runtime.h>

// Problem: B=4096 rows, N=16384 cols, fp32.
// out = where(outlier(x - roll(x,1,axis=1)), 0, nan_to_zero(x))
// lower/upper = mean_grad -/+ 4*sqrt(var_grad), per column.
//
// Structure: each block owns a 1024-column stripe (256 thr x float4) and a
// 32-row chunk. A thread's 4 columns are invariant across rows, so per-column
// bounds are computed ONCE into registers (kills 537 MB of L2 mean/var
// re-fetch and all per-row sqrtf), then 32 rows stream through a 4-row
// batched loop giving 8 independent loads in flight per thread.
// Grid = 16 stripes x 128 row-chunks = 2048 blocks = 8 WG/CU (full occupancy).

#define N_COLS 16384
#define N_MASK (N_COLS - 1)
#define COLS_PER_BLOCK 1024          // 256 threads * 4 floats
#define ROWS_PER_BLOCK 32

__device__ __forceinline__ float nan_clean(float v) {
    unsigned u = __float_as_uint(v);
    // exponent all-ones => NaN or Inf => 0
    return ((u & 0x7f800000u) == 0x7f800000u) ? 0.0f : v;
}

struct Bounds { float lo0, hi0, lo1, hi1, lo2, hi2, lo3, hi3; };

__device__ __forceinline__ float4 correct4(float4 a, float p, const Bounds& b) {
    float c0 = nan_clean(a.x);
    float c1 = nan_clean(a.y);
    float c2 = nan_clean(a.z);
    float c3 = nan_clean(a.w);
    float cp = nan_clean(p);

    float d0 = c0 - cp;
    float d1 = c1 - c0;
    float d2 = c2 - c1;
    float d3 = c3 - c2;

    float4 o;
    o.x = (d0 < b.lo0 || d0 > b.hi0) ? 0.0f : c0;
    o.y = (d1 < b.lo1 || d1 > b.hi1) ? 0.0f : c1;
    o.z = (d2 < b.lo2 || d2 > b.hi2) ? 0.0f : c2;
    o.w = (d3 < b.lo3 || d3 > b.hi3) ? 0.0f : c3;
    return o;
}

__global__ __launch_bounds__(256) void correction_kernel(
    const float* __restrict__ x,
    const float* __restrict__ mean_grad,
    const float* __restrict__ var_grad,
    float* __restrict__ out)
{
    // this thread's 4 columns (fixed for all rows it processes)
    const int c     = (blockIdx.x << 10) | (threadIdx.x << 2);
    const int cprev = (c - 1) & N_MASK;          // circular previous column

    // per-column bounds, computed once, live in 8 VGPRs for the whole block
    float4 m4 = *(const float4*)(mean_grad + c);
    float4 v4 = *(const float4*)(var_grad + c);
    Bounds b;
    float s;
    s = 4.0f * sqrtf(v4.x); b.lo0 = m4.x - s; b.hi0 = m4.x + s;
    s = 4.0f * sqrtf(v4.y); b.lo1 = m4.y - s; b.hi1 = m4.y + s;
    s = 4.0f * sqrtf(v4.z); b.lo2 = m4.z - s; b.hi2 = m4.z + s;
    s = 4.0f * sqrtf(v4.w); b.lo3 = m4.w - s; b.hi3 = m4.w + s;

    const long rowbase = (long)blockIdx.y * ROWS_PER_BLOCK * N_COLS;
    const float* xr = x + rowbase;
    float*       orow = out + rowbase;

    for (int rr = 0; rr < ROWS_PER_BLOCK; rr += 4) {
        // batch 4 rows: 8 independent loads in flight before any compute
        float4 a0 = *(const float4*)(xr + c);
        float  p0 = xr[cprev];
        float4 a1 = *(const float4*)(xr + N_COLS + c);
        float  p1 = xr[N_COLS + cprev];
        float4 a2 = *(const float4*)(xr + 2 * N_COLS + c);
        float  p2 = xr[2 * N_COLS + cprev];
        float4 a3 = *(const float4*)(xr + 3 * N_COLS + c);
        float  p3 = xr[3 * N_COLS + cprev];

        *(float4*)(orow + c)              = correct4(a0, p0, b);
        *(float4*)(orow + N_COLS + c)     = correct4(a1, p1, b);
        *(float4*)(orow + 2 * N_COLS + c) = correct4(a2, p2, b);
        *(float4*)(orow + 3 * N_COLS + c) = correct4(a3, p3, b);

        xr   += 4 * N_COLS;
        orow += 4 * N_COLS;
    }
}

extern "C" void kernel_launch(void* const* d_in, const int* in_sizes, int n_in,
                              void* d_out, int out_size, void* d_ws, size_t ws_size,
                              hipStream_t stream) {
    const float* x  = (const float*)d_in[0];   // output    [B, N]
    const float* mg = (const float*)d_in[1];   // mean_grad [N]
    const float* vg = (const float*)d_in[2];   // var_grad  [N]
    float* out = (float*)d_out;

    int B = in_sizes[0] / N_COLS;              // 4096
    dim3 grid(N_COLS / COLS_PER_BLOCK,         // 16 stripes
              B / ROWS_PER_BLOCK);             // 128 row-chunks -> 2048 blocks

    correction_kernel<<<grid, dim3(256), 0, stream>>>(x, mg, vg, out);
}

// Round 3
// 427.055 us; speedup vs baseline: 1.0496x; 1.0496x over previous
//
#include <hip/hip_runtime.h>

// Problem: B=4096 rows, N=16384 cols, fp32.
// out = where(outlier(x - roll(x,1,axis=1)), 0, nan_to_zero(x))
// lower/upper = mean_grad -/+ 4*sqrt(var_grad), per column.
//
// Structure (round-0 proven): one thread per float4, linear grid -> waves
// launch/retire in address order, dense sequential HBM frontier (~90 us).
// Round-1 lesson: 32-row blocking with an exactly-resident grid scattered
// the frontier and cost +30%; reverted.
// This round: (1) prev element via __shfl_up (lane t-1's cleaned c3) --
// only lane 0 per wave still loads; (2) non-temporal store for out
// (never re-read; keeps x lines live in L2 for the lane-0 prev loads).
// Round-2 fix: nt-store builtin needs a clang ext_vector_type, not HIP float4.

#define N_COLS 16384
#define N_MASK (N_COLS - 1)
#define COLS4_SHIFT 12               // log2(16384/4)
#define COLS4_MASK  ((N_COLS / 4) - 1)

typedef float f32x4 __attribute__((ext_vector_type(4)));

__device__ __forceinline__ float nan_clean(float v) {
    unsigned u = __float_as_uint(v);
    // exponent all-ones => NaN or Inf => 0
    return ((u & 0x7f800000u) == 0x7f800000u) ? 0.0f : v;
}

__global__ __launch_bounds__(256) void correction_kernel(
    const float* __restrict__ x,
    const float* __restrict__ mean_grad,
    const float* __restrict__ var_grad,
    float* __restrict__ out)
{
    int t = blockIdx.x * blockDim.x + threadIdx.x;
    int row  = t >> COLS4_SHIFT;
    int col4 = t & COLS4_MASK;
    int j    = col4 << 2;                      // starting column of this float4
    long base = (long)row * N_COLS + j;

    f32x4 x4 = *(const f32x4*)(x + base);

    float c0 = nan_clean(x4.x);
    float c1 = nan_clean(x4.y);
    float c2 = nan_clean(x4.z);
    float c3 = nan_clean(x4.w);

    // prev column value: lane l-1's c3 via cross-lane shuffle; only lane 0
    // of each wave falls back to an (exec-masked) scalar load.
    float cp = __shfl_up(c3, 1);
    if ((threadIdx.x & 63) == 0) {
        int jprev = (j + N_COLS - 1) & N_MASK;  // circular previous column
        cp = nan_clean(x[(long)row * N_COLS + jprev]);
    }

    // per-column bounds (128 KiB arrays, L1/L2-resident across all rows)
    f32x4 m4 = *(const f32x4*)(mean_grad + j);
    f32x4 v4 = *(const f32x4*)(var_grad + j);

    float s0 = 4.0f * sqrtf(v4.x);
    float s1 = 4.0f * sqrtf(v4.y);
    float s2 = 4.0f * sqrtf(v4.z);
    float s3 = 4.0f * sqrtf(v4.w);

    float d0 = c0 - cp;
    float d1 = c1 - c0;
    float d2 = c2 - c1;
    float d3 = c3 - c2;

    f32x4 o;
    o.x = (d0 < m4.x - s0 || d0 > m4.x + s0) ? 0.0f : c0;
    o.y = (d1 < m4.y - s1 || d1 > m4.y + s1) ? 0.0f : c1;
    o.z = (d2 < m4.z - s2 || d2 > m4.z + s2) ? 0.0f : c2;
    o.w = (d3 < m4.w - s3 || d3 > m4.w + s3) ? 0.0f : c3;

    __builtin_nontemporal_store(o, (f32x4*)(out + base));
}

extern "C" void kernel_launch(void* const* d_in, const int* in_sizes, int n_in,
                              void* d_out, int out_size, void* d_ws, size_t ws_size,
                              hipStream_t stream) {
    const float* x  = (const float*)d_in[0];   // output    [B, N]
    const float* mg = (const float*)d_in[1];   // mean_grad [N]
    const float* vg = (const float*)d_in[2];   // var_grad  [N]
    float* out = (float*)d_out;

    int B = in_sizes[0] / N_COLS;              // 4096
    long total_threads = (long)B * (N_COLS / 4);
    int block = 256;
    int grid = (int)((total_threads + block - 1) / block);

    correction_kernel<<<grid, block, 0, stream>>>(x, mg, vg, out);
}